// Round 4
// baseline (9571.581 us; speedup 1.0000x reference)
//
#include <hip/hip_runtime.h>
#include <hip/hip_bf16.h>

#define TT 1024
#define BB 64
#define II 256
#define HH 512
#define OO 128

typedef __attribute__((ext_vector_type(4))) float f32x4;
typedef __attribute__((ext_vector_type(4))) int   i32x4;
typedef __attribute__((ext_vector_type(2))) unsigned long long u64x2;
typedef __attribute__((ext_vector_type(8))) __bf16 bf16x8;
typedef __attribute__((ext_vector_type(8))) short s16x8;
typedef unsigned long long u64;
typedef unsigned short u16;
typedef unsigned int u32;

// smem: K-split partials at 0 (<=64KB); L1 bias @132096; head scratch [64][516]f32 = 132096B.
#define BIAS_OFF 132096
#define SMEM_BYTES 132608

static __device__ __forceinline__ u16 f2b(float f) { return __builtin_bit_cast(u16, (__bf16)f); }
static __device__ __forceinline__ float b2f(u16 u) { return (float)__builtin_bit_cast(__bf16, u); }

static __device__ __forceinline__ u64 pack4f(float a, float b, float c, float d) {
    return (u64)f2b(a) | ((u64)f2b(b) << 16) | ((u64)f2b(c) << 32) | ((u64)f2b(d) << 48);
}
static __device__ __forceinline__ bf16x8 cvt8(f32x4 a0, f32x4 a1) {
    bf16x8 v;
    v[0]=(__bf16)a0[0]; v[1]=(__bf16)a0[1]; v[2]=(__bf16)a0[2]; v[3]=(__bf16)a0[3];
    v[4]=(__bf16)a1[0]; v[5]=(__bf16)a1[1]; v[6]=(__bf16)a1[2]; v[7]=(__bf16)a1[3];
    return v;
}
static __device__ __forceinline__ bf16x8 mk8(u64 lo, u64 hi) {
    u64x2 v; v[0] = lo; v[1] = hi;
    return __builtin_bit_cast(bf16x8, v);
}
static __device__ __forceinline__ int ald32(const int* p) {
    return __hip_atomic_load(p, __ATOMIC_RELAXED, __HIP_MEMORY_SCOPE_AGENT);
}
static __device__ __forceinline__ u64 ald(const u64* p) {
    return __hip_atomic_load(p, __ATOMIC_RELAXED, __HIP_MEMORY_SCOPE_AGENT);
}
static __device__ __forceinline__ void ast(u64* p, u64 v) {
    __hip_atomic_store(p, v, __ATOMIC_RELAXED, __HIP_MEMORY_SCOPE_AGENT);
}

// ---------------- Phase A: XB[t][b][n] = x_t @ W_ih0^T + b_ih0 + b_hh0 (bf16) ----
__global__ __launch_bounds__(512, 2) void xproj_kernel(
    const float* __restrict__ x, const float* __restrict__ Wih0,
    const float* __restrict__ bih0, const float* __restrict__ bhh0,
    u64* __restrict__ XBu)
{
    const int tid = threadIdx.x;
    const int l = tid & 63, w = tid >> 6;
    const int lm = l & 15, lg = l >> 4;
    const int t = blockIdx.x * 4 + (w >> 1);
    const int nh = w & 1;

    bf16x8 xf[4][8];
    #pragma unroll
    for (int bt = 0; bt < 4; ++bt) {
        const float* xb = x + (size_t)(bt * 16 + lm) * (TT * II) + (size_t)t * II + lg * 8;
        #pragma unroll
        for (int kt = 0; kt < 8; ++kt) {
            f32x4 a0 = *(const f32x4*)(xb + kt * 32);
            f32x4 a1 = *(const f32x4*)(xb + kt * 32 + 4);
            xf[bt][kt] = cvt8(a0, a1);
        }
    }
    for (int nt = 0; nt < 16; ++nt) {
        const int n_row = nh * 256 + nt * 16 + lm;
        bf16x8 wf[8];
        #pragma unroll
        for (int kt = 0; kt < 8; ++kt) {
            const float* wsrc = Wih0 + (size_t)n_row * II + kt * 32 + lg * 8;
            f32x4 a0 = *(const f32x4*)(wsrc);
            f32x4 a1 = *(const f32x4*)(wsrc + 4);
            wf[kt] = cvt8(a0, a1);
        }
        f32x4 acc[4] = {{0,0,0,0},{0,0,0,0},{0,0,0,0},{0,0,0,0}};
        #pragma unroll
        for (int kt = 0; kt < 8; ++kt)
            #pragma unroll
            for (int bt = 0; bt < 4; ++bt)
                acc[bt] = __builtin_amdgcn_mfma_f32_16x16x32_bf16(wf[kt], xf[bt][kt], acc[bt], 0, 0, 0);
        const int n0 = nh * 256 + nt * 16 + lg * 4;
        f32x4 bias = *(const f32x4*)(bih0 + n0);
        f32x4 bias2 = *(const f32x4*)(bhh0 + n0);
        #pragma unroll
        for (int bt = 0; bt < 4; ++bt) {
            const int b = bt * 16 + lm;
            XBu[((size_t)t * 64 + b) * 128 + (n0 >> 2)] =
                pack4f(acc[bt][0] + bias[0] + bias2[0], acc[bt][1] + bias[1] + bias2[1],
                       acc[bt][2] + bias[2] + bias2[2], acc[bt][3] + bias[3] + bias2[3]);
        }
    }
}

// ---------------- Phase B: persistent recurrent workers, fence-free ------------
// 16 blocks: 0-7 layer0, 8-15 layer1, n-slice of 64 each. Weights in VGPRs.
// h slots: 4-deep [64][128 u64] per layer in ws. All cross-block data via
// agent-scope relaxed atomics (cache-bypassing); ordering via vmcnt drain +
// barrier before the counter add. NO fences -> no L1/L2 invalidation.
template <int L>
static __device__ void run_layer(const u16* __restrict__ XB,
                                 const float* __restrict__ hinit,
                                 const float* __restrict__ Wi,   // L0: Whh0; L1: Wih1
                                 const float* __restrict__ Wh,   // L1: Whh1
                                 const float* __restrict__ bi, const float* __restrict__ bh,
                                 int* cnt0, int* cnt1,
                                 u64* h0s, u64* h1s,
                                 int nb, char* smem)
{
    constexpr int WKG = (L == 0) ? 2 : 4;      // K-split groups
    constexpr int MTW = (L == 0) ? 1 : 2;      // m-tiles per wave

    const int tid = threadIdx.x;
    const int l = tid & 63, w = tid >> 6;
    const int lm = l & 15, lg = l >> 4;
    const int wm = (L == 0) ? (w & 3) : (w & 1);
    const int wk = (L == 0) ? (w >> 2) : (w >> 1);
    u64* wbase = (L == 0) ? h0s : h1s;
    int* mycnt = (L == 0) ? cnt0 : cnt1;

    // ---- init: initial hidden slice (cols [nb,nb+64)) -> slot 3
    {
        const int m = tid >> 3, c8 = tid & 7;
        const float* s = hinit + (size_t)m * HH + nb + c8 * 8;
        u64* d = &wbase[3 * 8192 + m * 128 + (nb >> 2) + c8 * 2];
        ast(&d[0], pack4f(s[0], s[1], s[2], s[3]));
        ast(&d[1], pack4f(s[4], s[5], s[6], s[7]));
    }
    if (L == 1 && tid < 64)
        ((float*)(smem + BIAS_OFF))[tid] = bi[nb + tid] + bh[nb + tid];
    asm volatile("s_waitcnt vmcnt(0)" ::: "memory");
    __syncthreads();
    if (tid == 0)
        __hip_atomic_fetch_add(mycnt, 1, __ATOMIC_RELAXED, __HIP_MEMORY_SCOPE_AGENT);

    // ---- B-fragments (weights) -> registers, zero-duplication partition
    bf16x8 B[4][8];
    #pragma unroll
    for (int nt = 0; nt < 4; ++nt) {
        const int n = nb + nt * 16 + lm;
        #pragma unroll
        for (int ktl = 0; ktl < 8; ++ktl) {
            const int ktg = wk * 8 + ktl;
            const float* src;
            if (L == 0) src = Wi + (size_t)n * HH + ktg * 32 + lg * 8;
            else        src = (ktg < 16) ? (Wi + (size_t)n * HH + ktg * 32 + lg * 8)
                                         : (Wh + (size_t)n * HH + (ktg - 16) * 32 + lg * 8);
            f32x4 a0 = *(const f32x4*)(src);
            f32x4 a1 = *(const f32x4*)(src + 4);
            B[nt][ktl] = cvt8(a0, a1);
        }
    }

    float* part = (float*)smem;

    for (int t = 0; t < TT; ++t) {
        f32x4 acc[MTW][4];
        #pragma unroll
        for (int i = 0; i < MTW; ++i)
            #pragma unroll
            for (int nt = 0; nt < 4; ++nt) acc[i][nt] = f32x4{0, 0, 0, 0};

        if (L == 0) {
            // per-wave spin: h0[t-1] ready (+ slot-reuse anti-dep vs L1 readers)
            const int tgt = 8 * (t + 1);
            while (ald32(cnt0) < tgt) {}
            if (t >= 4) { const int tg1 = 8 * (t - 2); while (ald32(cnt1) < tg1) {} }
            asm volatile("" ::: "memory");
            // direct A-frag loads: row m, k-cols of this wave's wk group
            const u64* sp = h0s + ((t + 3) & 3) * 8192
                          + (wm * 16 + lm) * 128 + wk * 64 + lg * 2;
            u64 pa[8][2];
            #pragma unroll
            for (int ktl = 0; ktl < 8; ++ktl) {
                pa[ktl][0] = ald(sp + ktl * 8);
                pa[ktl][1] = ald(sp + ktl * 8 + 1);
            }
            #pragma unroll
            for (int ktl = 0; ktl < 8; ++ktl) {
                bf16x8 a = mk8(pa[ktl][0], pa[ktl][1]);
                #pragma unroll
                for (int nt = 0; nt < 4; ++nt)
                    acc[0][nt] = __builtin_amdgcn_mfma_f32_16x16x32_bf16(a, B[nt][ktl], acc[0][nt], 0, 0, 0);
            }
        } else {
            if (wk >= 2) {
                // Whh1 half: needs only h1[t-1] -> runs ahead of h0[t] arrival
                const int tgt = 8 * (t + 1);
                while (ald32(cnt1) < tgt) {}
                asm volatile("" ::: "memory");
                const u64* sp = h1s + ((t + 3) & 3) * 8192 + (wk - 2) * 64 + lg * 2;
                #pragma unroll
                for (int i = 0; i < MTW; ++i) {
                    const u64* spm = sp + ((wm * 2 + i) * 16 + lm) * 128;
                    u64 pa[8][2];
                    #pragma unroll
                    for (int ktl = 0; ktl < 8; ++ktl) {
                        pa[ktl][0] = ald(spm + ktl * 8);
                        pa[ktl][1] = ald(spm + ktl * 8 + 1);
                    }
                    #pragma unroll
                    for (int ktl = 0; ktl < 8; ++ktl) {
                        bf16x8 a = mk8(pa[ktl][0], pa[ktl][1]);
                        #pragma unroll
                        for (int nt = 0; nt < 4; ++nt)
                            acc[i][nt] = __builtin_amdgcn_mfma_f32_16x16x32_bf16(a, B[nt][ktl], acc[i][nt], 0, 0, 0);
                    }
                }
            } else {
                // Wih1 half: needs h0[t]
                const int tgt = 8 * (t + 2);
                while (ald32(cnt0) < tgt) {}
                asm volatile("" ::: "memory");
                const u64* sp = h0s + (t & 3) * 8192 + wk * 64 + lg * 2;
                #pragma unroll
                for (int i = 0; i < MTW; ++i) {
                    const u64* spm = sp + ((wm * 2 + i) * 16 + lm) * 128;
                    u64 pa[8][2];
                    #pragma unroll
                    for (int ktl = 0; ktl < 8; ++ktl) {
                        pa[ktl][0] = ald(spm + ktl * 8);
                        pa[ktl][1] = ald(spm + ktl * 8 + 1);
                    }
                    #pragma unroll
                    for (int ktl = 0; ktl < 8; ++ktl) {
                        bf16x8 a = mk8(pa[ktl][0], pa[ktl][1]);
                        #pragma unroll
                        for (int nt = 0; nt < 4; ++nt)
                            acc[i][nt] = __builtin_amdgcn_mfma_f32_16x16x32_bf16(a, B[nt][ktl], acc[i][nt], 0, 0, 0);
                    }
                }
            }
        }

        // ---- K-split partials -> LDS
        #pragma unroll
        for (int i = 0; i < MTW; ++i)
            #pragma unroll
            for (int nt = 0; nt < 4; ++nt)
                #pragma unroll
                for (int r = 0; r < 4; ++r) {
                    const int m = (wm * MTW + i) * 16 + lg * 4 + r;
                    part[(wk * 64 + m) * 64 + nt * 16 + lm] = acc[i][nt][r];
                }
        __syncthreads();

        // ---- epilogue: reduce + bias/XB + tanh + pack + publish
        {
            const int m = tid >> 3, c0 = (tid & 7) * 8;
            f32x4 sa = {0, 0, 0, 0}, sb = {0, 0, 0, 0};
            #pragma unroll
            for (int k = 0; k < WKG; ++k) {
                const float* pr = part + (k * 64 + m) * 64 + c0;
                sa += *(const f32x4*)pr;
                sb += *(const f32x4*)(pr + 4);
            }
            float e[8];
            if (L == 0) {
                const s16x8 xv = *(const s16x8*)(XB + ((size_t)t * 64 + m) * 512 + nb + c0);
                #pragma unroll
                for (int r = 0; r < 4; ++r) {
                    e[r] = sa[r] + b2f((u16)xv[r]);
                    e[4 + r] = sb[r] + b2f((u16)xv[4 + r]);
                }
            } else {
                const float* bl = (const float*)(smem + BIAS_OFF) + c0;
                #pragma unroll
                for (int r = 0; r < 4; ++r) {
                    e[r] = sa[r] + bl[r];
                    e[4 + r] = sb[r] + bl[4 + r];
                }
            }
            u64* d = &wbase[(t & 3) * 8192 + m * 128 + (nb >> 2) + (tid & 7) * 2];
            ast(&d[0], pack4f(tanhf(e[0]), tanhf(e[1]), tanhf(e[2]), tanhf(e[3])));
            ast(&d[1], pack4f(tanhf(e[4]), tanhf(e[5]), tanhf(e[6]), tanhf(e[7])));
        }
        asm volatile("s_waitcnt vmcnt(0)" ::: "memory");
        __syncthreads();   // all stores acked before the signal
        if (tid == 0)
            __hip_atomic_fetch_add(mycnt, 1, __ATOMIC_RELAXED, __HIP_MEMORY_SCOPE_AGENT);
    }
}

// Final Linear head on h1[T-1]; 8 layer-1 blocks, 16 out-cols each.
static __device__ void head_phase(const float* __restrict__ Wout,
                                  const float* __restrict__ bout,
                                  const u64* __restrict__ h1slot,
                                  float* __restrict__ out,
                                  int obase, int* cnt1, char* smem)
{
    const int tid = threadIdx.x;
    if (tid == 0) { while (ald32(cnt1) < 8 * (TT + 1)) {} }
    __syncthreads();
    asm volatile("" ::: "memory");
    float* hf = (float*)smem;                 // [64][516] padded f32
    for (int q = tid; q < 8192; q += 512) {
        u64 v = ald(&h1slot[q]);
        const int m = q >> 7, c4 = (q & 127) * 4;
        float* d = hf + m * 516 + c4;
        d[0] = b2f((u16)v);         d[1] = b2f((u16)(v >> 16));
        d[2] = b2f((u16)(v >> 32)); d[3] = b2f((u16)(v >> 48));
    }
    __syncthreads();
    const int b = tid >> 3, oo = tid & 7;
    const float* hrow = hf + b * 516;
    #pragma unroll
    for (int h = 0; h < 2; ++h) {
        const int o = obase + oo + h * 8;
        const float* wr = Wout + (size_t)o * HH;
        float acc = 0.f;
        #pragma unroll 4
        for (int k4 = 0; k4 < 128; ++k4) {
            f32x4 wv = *(const f32x4*)(wr + k4 * 4);
            f32x4 hv = *(const f32x4*)(hrow + k4 * 4);
            acc += wv[0]*hv[0] + wv[1]*hv[1] + wv[2]*hv[2] + wv[3]*hv[3];
        }
        out[b * OO + o] = acc + bout[o];
    }
}

__global__ __launch_bounds__(512, 2) void rnn_persist(
    const u16* __restrict__ XB,
    const float* __restrict__ h0init,
    const float* __restrict__ Whh0,
    const float* __restrict__ Wih1, const float* __restrict__ bih1,
    const float* __restrict__ Whh1, const float* __restrict__ bhh1,
    const float* __restrict__ Wout, const float* __restrict__ bout,
    float* __restrict__ out, int* __restrict__ cnt, u64* __restrict__ hbuf)
{
    __shared__ __align__(16) char smem[SMEM_BYTES];
    const int bx = blockIdx.x;
    int* cnt0 = cnt;
    int* cnt1 = cnt + 32;
    u64* h0s = hbuf;
    u64* h1s = hbuf + 4 * 8192;
    if (bx < 8) {
        run_layer<0>(XB, h0init, Whh0, nullptr, nullptr, nullptr,
                     cnt0, cnt1, h0s, h1s, bx * 64, smem);
    } else {
        run_layer<1>(nullptr, h0init + BB * HH, Wih1, Whh1, bih1, bhh1,
                     cnt0, cnt1, h0s, h1s, (bx - 8) * 64, smem);
        head_phase(Wout, bout, h1s + 3 * 8192, out, (bx - 8) * 16, cnt1, smem);
    }
}

extern "C" void kernel_launch(void* const* d_in, const int* in_sizes, int n_in,
                              void* d_out, int out_size, void* d_ws, size_t ws_size,
                              hipStream_t stream) {
    const float* x     = (const float*)d_in[0];
    const float* h0i   = (const float*)d_in[1];
    const float* Wih0  = (const float*)d_in[2];
    const float* bih0  = (const float*)d_in[3];
    const float* Whh0  = (const float*)d_in[4];
    const float* bhh0  = (const float*)d_in[5];
    const float* Wih1  = (const float*)d_in[6];
    const float* bih1  = (const float*)d_in[7];
    const float* Whh1  = (const float*)d_in[8];
    const float* bhh1  = (const float*)d_in[9];
    const float* Wout  = (const float*)d_in[10];
    const float* bout  = (const float*)d_in[11];
    float* out = (float*)d_out;

    int* cnt  = (int*)d_ws;                             // counters
    u64* hbuf = (u64*)((char*)d_ws + 256);              // 2 layers x 4 slots x 64KB
    u16* XB   = (u16*)((char*)d_ws + (1 << 20));        // 64MB bf16 [T][B][H]

    hipMemsetAsync(d_ws, 0, 256, stream);
    xproj_kernel<<<256, 512, 0, stream>>>(x, Wih0, bih0, bhh0, (u64*)XB);

    void* args[] = { &XB, &h0i, &Whh0, &Wih1, &bih1, &Whh1, &bhh1,
                     &Wout, &bout, &out, &cnt, &hbuf };
    hipLaunchCooperativeKernel((const void*)rnn_persist, dim3(16), dim3(512),
                               args, 0, stream);
}